// Round 15
// baseline (1388.224 us; speedup 1.0000x reference)
//
#include <hip/hip_runtime.h>
#include <hip/hip_bf16.h>
#include <math.h>

#define N_TOK 2048
#define DIM   2048
#define NH    16
#define NOPE  128
#define ROPE_D 64
#define QKH   192
#define VH    128
#define KVR   512
#define INTER 5632
#define VOCAB 32000
#define NLAYER 2
#define EPS   1e-6f

typedef __hip_bfloat16 bf16;
typedef __bf16 bf16x8 __attribute__((ext_vector_type(8)));
typedef float  f32x4  __attribute__((ext_vector_type(4)));

__device__ __forceinline__ float bf2f(unsigned short u) {
    union { unsigned u; float f; } a; a.u = ((unsigned)u) << 16; return a.f;
}
__device__ __forceinline__ unsigned short f2bfu(float f) {
    union { float f; unsigned u; } a; a.f = f;
    return (unsigned short)((a.u + 0x7fffu + ((a.u >> 16) & 1u)) >> 16);
}

__device__ __forceinline__ void gload16(const void* g, void* l) {
    __builtin_amdgcn_global_load_lds((const __attribute__((address_space(1))) void*)g,
                                     (__attribute__((address_space(3))) void*)l, 16, 0, 0);
}

// ---------------- embedding gather ----------------
__global__ void k_embed(const int* __restrict__ tokens, const float* __restrict__ emb,
                        float* __restrict__ h) {
    int n = blockIdx.x;
    int t = tokens[n];
    const float4* src = (const float4*)(emb + (size_t)t * DIM);
    float4* dst = (float4*)(h + (size_t)n * DIM);
    for (int i = threadIdx.x; i < DIM / 4; i += blockDim.x) dst[i] = src[i];
}

// ---------------- rmsnorm f32 -> bf16 ----------------
__global__ __launch_bounds__(256) void k_rmsnorm(const float* __restrict__ in, int in_stride, int in_off,
                                                 bf16* __restrict__ out, const float* __restrict__ w,
                                                 int len) {
    int row = blockIdx.x;
    const float* x = in + (size_t)row * in_stride + in_off;
    float ss = 0.f;
    for (int i = threadIdx.x; i < len; i += 256) { float v = x[i]; ss += v * v; }
    for (int off = 32; off > 0; off >>= 1) ss += __shfl_down(ss, off, 64);
    __shared__ float red[4];
    if ((threadIdx.x & 63) == 0) red[threadIdx.x >> 6] = ss;
    __syncthreads();
    float tot = red[0] + red[1] + red[2] + red[3];
    float inv = rsqrtf(tot / (float)len + EPS);
    for (int i = threadIdx.x; i < len; i += 256)
        out[(size_t)row * len + i] = __float2bfloat16(x[i] * inv * w[i]);
}

// ---------------- conv body: W[K][ncols] f32 (col base c0) -> Out bf16 [n][K] ----------------
__device__ __forceinline__ void conv_body(const float* __restrict__ W, bf16* __restrict__ Out,
                                          int K, int ldw, int ncols, int c0, int ilv,
                                          int bx, int by) {
    __shared__ float T[32][65];
    int n0 = bx * 64, k0 = by * 32;
    int tid = threadIdx.x;
    int rr = tid >> 4, cc = (tid & 15) * 4;
#pragma unroll
    for (int p = 0; p < 2; ++p) {
        int k = k0 + rr + p * 16;
        float4 v = make_float4(0.f, 0.f, 0.f, 0.f);
        if (n0 + cc < ncols) v = *(const float4*)(W + (size_t)k * ldw + c0 + n0 + cc);
        T[rr + p * 16][cc + 0] = v.x; T[rr + p * 16][cc + 1] = v.y;
        T[rr + p * 16][cc + 2] = v.z; T[rr + p * 16][cc + 3] = v.w;
    }
    __syncthreads();
    int n = tid >> 2, kc = (tid & 3) * 8;
    __align__(16) bf16 tmp[8];
#pragma unroll
    for (int e = 0; e < 8; ++e) tmp[e] = __float2bfloat16(T[kc + e][n]);
    int nl = n0 + n;
    int prow = (ilv < 0) ? nl : (((nl >> 4) << 5) + (nl & 15) + ilv);
    *(int4*)(Out + (size_t)prow * K + k0 + kc) = *(const int4*)tmp;
}

__global__ __launch_bounds__(256)
void k_convT(const float* __restrict__ W, bf16* __restrict__ Out,
             int K, int ldw, int ncols, int c0, int ilv) {
    conv_body(W, Out, K, ldw, ncols, c0, ilv, blockIdx.x, blockIdx.y);
}

// ---------------- batched weight conversion ----------------
struct ConvBatch {
    const float* W[7];
    bf16* Out[7];
    int K[7], ldw[7], ncols[7], ilv[7], nbx[7];
    int blk0[8];
};

__global__ __launch_bounds__(256) void k_convAll(ConvBatch cb) {
    int bid = blockIdx.x;
    int seg = 0;
#pragma unroll
    for (int i = 1; i < 7; ++i) if (bid >= cb.blk0[i]) seg = i;
    int rem = bid - cb.blk0[seg];
    int bx = rem % cb.nbx[seg], by = rem / cb.nbx[seg];
    conv_body(cb.W[seg], cb.Out[seg], cb.K[seg], cb.ldw[seg], cb.ncols[seg], 0, cb.ilv[seg],
              bx, by);
}

// ---------------- bf16 MFMA GEMM, 128x128 tile, ring-4 LDS, counted vmcnt ----------------
// OUT: 0=f32 store, 1=f32 +=, 3=silu(w1)*w2 on ilv-16 B -> bf16 [M][N/2],
//      4=split pack (Cv=Kb nope, Cv2=Vt [h][d][key] direct).
#define TILE4(u, DOSTAGE, GATE) { \
    const int t = t0 + (u); \
    const bf16* sAb = sA_ + (u) * 4096; \
    const bf16* sBb = sB_ + (u) * 4096; \
    bf16* dA = sA_ + (((u) + 3) & 3) * 4096; \
    bf16* dB = sB_ + (((u) + 3) & 3) * 4096; \
    if (DOSTAGE) { \
        size_t kk = (size_t)(t + 3) * 32; \
        gload16(A + (size_t)(row0 + srow) * lda + kk + scol * 8, dA + tid * 8); \
        gload16(A + (size_t)(row0 + 64 + srow) * lda + kk + scol * 8, dA + 2048 + tid * 8); \
    } \
    bf16x8 av0[2], bv[4]; \
    _Pragma("unroll") \
    for (int m = 0; m < 2; ++m) \
        av0[m] = *(const bf16x8*)(sAb + (wm + m * 16 + fr) * 32 + swz); \
    _Pragma("unroll") \
    for (int n = 0; n < 4; ++n) \
        bv[n] = *(const bf16x8*)(sBb + (wn + n * 16 + fr) * 32 + swz); \
    __builtin_amdgcn_s_barrier(); \
    __builtin_amdgcn_s_setprio(1); \
    _Pragma("unroll") \
    for (int m = 0; m < 2; ++m) { \
        acc[m][0] = __builtin_amdgcn_mfma_f32_16x16x32_bf16(av0[m], bv[0], acc[m][0], 0, 0, 0); \
        acc[m][1] = __builtin_amdgcn_mfma_f32_16x16x32_bf16(av0[m], bv[1], acc[m][1], 0, 0, 0); \
        acc[m][2] = __builtin_amdgcn_mfma_f32_16x16x32_bf16(av0[m], bv[2], acc[m][2], 0, 0, 0); \
        acc[m][3] = __builtin_amdgcn_mfma_f32_16x16x32_bf16(av0[m], bv[3], acc[m][3], 0, 0, 0); \
    } \
    __builtin_amdgcn_s_setprio(0); \
    __builtin_amdgcn_s_barrier(); \
    if (DOSTAGE) { \
        size_t kk = (size_t)(t + 3) * 32; \
        gload16(Bt + (size_t)(col0 + srow) * ldb + kk + scol * 8, dB + tid * 8); \
        gload16(Bt + (size_t)(col0 + 64 + srow) * ldb + kk + scol * 8, dB + 2048 + tid * 8); \
    } \
    bf16x8 av1[2]; \
    _Pragma("unroll") \
    for (int m = 0; m < 2; ++m) \
        av1[m] = *(const bf16x8*)(sAb + (wm + (m + 2) * 16 + fr) * 32 + swz); \
    __builtin_amdgcn_s_barrier(); \
    __builtin_amdgcn_s_setprio(1); \
    _Pragma("unroll") \
    for (int m = 0; m < 2; ++m) { \
        acc[m + 2][0] = __builtin_amdgcn_mfma_f32_16x16x32_bf16(av1[m], bv[0], acc[m + 2][0], 0, 0, 0); \
        acc[m + 2][1] = __builtin_amdgcn_mfma_f32_16x16x32_bf16(av1[m], bv[1], acc[m + 2][1], 0, 0, 0); \
        acc[m + 2][2] = __builtin_amdgcn_mfma_f32_16x16x32_bf16(av1[m], bv[2], acc[m + 2][2], 0, 0, 0); \
        acc[m + 2][3] = __builtin_amdgcn_mfma_f32_16x16x32_bf16(av1[m], bv[3], acc[m + 2][3], 0, 0, 0); \
    } \
    __builtin_amdgcn_s_setprio(0); \
    GATE; \
    __builtin_amdgcn_s_barrier(); \
    __builtin_amdgcn_sched_barrier(0); \
}

template<int OUT>
__global__ __launch_bounds__(256, 2)
void k_mm(const bf16* __restrict__ A, const bf16* __restrict__ Bt, void* __restrict__ Cv,
          void* __restrict__ Cv2, int Nreal, int K, int lda, int ldb, int ldc) {
    extern __shared__ char smem_raw[];
    bf16* sA_ = (bf16*)smem_raw;            // 4 bufs x 128x32
    bf16* sB_ = sA_ + 4 * 4096;
    int cpx = gridDim.x >> 3;
    int logical = ((int)blockIdx.x & 7) * cpx + ((int)blockIdx.x >> 3);
    int row0 = (logical & 15) * 128, col0 = (logical >> 4) * 128;
    int tid = threadIdx.x;
    int lane = tid & 63, wave = tid >> 6;
    int wm = (wave & 1) * 64, wn = (wave >> 1) * 64;
    int fr = lane & 15, fg = lane >> 4;
    int srow = tid >> 2;
    int scol = (tid & 3) ^ ((srow >> 1) & 3);            // T2 staging source slot
    int swz = (fg ^ ((fr >> 1) & 3)) * 8;                // T2 read slot (elem offset)

    f32x4 acc[4][4] = {};
    int nt = K >> 5;

#pragma unroll
    for (int t = 0; t < 3; ++t) {
        size_t kk = (size_t)t * 32;
        bf16* dA = sA_ + t * 4096;
        bf16* dB = sB_ + t * 4096;
        gload16(A + (size_t)(row0 + srow) * lda + kk + scol * 8, dA + tid * 8);
        gload16(A + (size_t)(row0 + 64 + srow) * lda + kk + scol * 8, dA + 2048 + tid * 8);
        gload16(Bt + (size_t)(col0 + srow) * ldb + kk + scol * 8, dB + tid * 8);
        gload16(Bt + (size_t)(col0 + 64 + srow) * ldb + kk + scol * 8, dB + 2048 + tid * 8);
    }
    asm volatile("s_waitcnt vmcnt(8)" ::: "memory");
    __builtin_amdgcn_s_barrier();
    __builtin_amdgcn_sched_barrier(0);

    int ngroups = nt >> 2;
    for (int g = 0; g < ngroups - 1; ++g) {
        int t0 = g * 4;
        TILE4(0, 1, asm volatile("s_waitcnt vmcnt(8)" ::: "memory"));
        TILE4(1, 1, asm volatile("s_waitcnt vmcnt(8)" ::: "memory"));
        TILE4(2, 1, asm volatile("s_waitcnt vmcnt(8)" ::: "memory"));
        TILE4(3, 1, asm volatile("s_waitcnt vmcnt(8)" ::: "memory"));
    }
    {
        int t0 = nt - 4;
        TILE4(0, 1, asm volatile("s_waitcnt vmcnt(8)" ::: "memory"));
        TILE4(1, 0, asm volatile("s_waitcnt vmcnt(4)" ::: "memory"));
        TILE4(2, 0, asm volatile("s_waitcnt vmcnt(0)" ::: "memory"));
        TILE4(3, 0, (void)0);
    }

    float* Cf = (float*)Cv;
    bf16* Cb = (bf16*)Cv;
    bf16* Vtp = (bf16*)Cv2;
    if (OUT == 3) {
        // silu(w1)*w2 on interleaved-16 pairs; output col-space is N/2
#pragma unroll
        for (int i = 0; i < 4; ++i)
#pragma unroll
            for (int p2 = 0; p2 < 2; ++p2)
#pragma unroll
                for (int q = 0; q < 4; ++q) {
                    int row = row0 + wm + i * 16 + fg * 4 + q;
                    int col = (col0 >> 1) + (wn >> 1) + p2 * 16 + fr;
                    float a = acc[i][2 * p2][q], b = acc[i][2 * p2 + 1][q];
                    float r = a / (1.f + __expf(-a)) * b;
                    Cb[(size_t)row * ldc + col] = __float2bfloat16(r);
                }
        return;
    }
#pragma unroll
    for (int i = 0; i < 4; ++i)
#pragma unroll
        for (int j = 0; j < 4; ++j)
#pragma unroll
            for (int q = 0; q < 4; ++q) {
                int row = row0 + wm + i * 16 + fg * 4 + q;
                int col = col0 + wn + j * 16 + fr;
                if (col < Nreal) {
                    if (OUT == 0) Cf[(size_t)row * ldc + col] = acc[i][j][q];
                    else if (OUT == 1) Cf[(size_t)row * ldc + col] += acc[i][j][q];
                    else {  // OUT == 4: kvb pack (K-nope + V transposed directly)
                        int head = col >> 8, d = col & 255;
                        if (d < NOPE)
                            Cb[(size_t)head * N_TOK * QKH + (size_t)row * QKH + d] =
                                __float2bfloat16(acc[i][j][q]);
                        else
                            Vtp[(size_t)head * VH * N_TOK + (size_t)(d - NOPE) * N_TOK + row] =
                                __float2bfloat16(acc[i][j][q]);
                    }
                }
            }
}

// ---------------- q rope+pack, Kb rope broadcast, AND kv rmsnorm -> cb (merged) ----------------
__global__ __launch_bounds__(256) void k_qpack(const float* __restrict__ q, int qstride, int kvoff,
        const float* __restrict__ cosb, const float* __restrict__ sinb,
        bf16* __restrict__ qb, bf16* __restrict__ Kb,
        const float* __restrict__ kvnw, bf16* __restrict__ cb) {
    int n = blockIdx.x;
    __shared__ float c[32], s[32];
    __shared__ float red[4];
    if (threadIdx.x < 32) {
        c[threadIdx.x] = cosb[n * 32 + threadIdx.x];
        s[threadIdx.x] = sinb[n * 32 + threadIdx.x];
    }
    __syncthreads();
    const float* row = q + (size_t)n * qstride;
    {
        float ss = 0.f;
        for (int i = threadIdx.x; i < KVR; i += 256) {
            float v = row[kvoff + 64 + i]; ss += v * v;
        }
        for (int off = 32; off > 0; off >>= 1) ss += __shfl_down(ss, off, 64);
        if ((threadIdx.x & 63) == 0) red[threadIdx.x >> 6] = ss;
        __syncthreads();
        float inv = rsqrtf((red[0] + red[1] + red[2] + red[3]) / (float)KVR + EPS);
        for (int i = threadIdx.x; i < KVR; i += 256)
            cb[(size_t)n * KVR + i] = __float2bfloat16(row[kvoff + 64 + i] * inv * kvnw[i]);
    }
    if (threadIdx.x < 32) {
        int i = threadIdx.x;
        float xr = row[kvoff + 2 * i], xi = row[kvoff + 2 * i + 1];
        float r0 = xr * c[i] - xi * s[i];
        float r1 = xr * s[i] + xi * c[i];
        unsigned pk = (unsigned)f2bfu(r0) | ((unsigned)f2bfu(r1) << 16);
#pragma unroll
        for (int hh = 0; hh < NH; ++hh)
            *(unsigned*)(Kb + (size_t)hh * N_TOK * QKH + (size_t)n * QKH + NOPE + 2 * i) = pk;
    }
    for (int idx = threadIdx.x; idx < NH * QKH; idx += 256) {
        int h = idx / QKH, d = idx - h * QKH;
        float v;
        if (d < NOPE) v = row[idx];
        else {
            int i = (d - NOPE) >> 1;
            float xr = row[h * QKH + NOPE + 2 * i], xi = row[h * QKH + NOPE + 2 * i + 1];
            v = ((d & 1) == 0) ? xr * c[i] - xi * s[i] : xr * s[i] + xi * c[i];
        }
        qb[(size_t)h * (N_TOK * QKH) + (size_t)n * QKH + d] = __float2bfloat16(v);
    }
}

// ---------------- fused flash attention, QBLK=32, 2 waves, paired panels ----------------
__global__ __launch_bounds__(128, 2)
void k_flash(const bf16* __restrict__ qb, const bf16* __restrict__ Kb,
             const bf16* __restrict__ Vt, bf16* __restrict__ aout) {
    int h = blockIdx.x, yp = blockIdx.y;
    __shared__ short Ks[64 * 200];
    __shared__ short Vs[128 * 72];
    __shared__ short Ps[32 * 72];
    int t = threadIdx.x;
    int lane = t & 63, w = t >> 6;
    int fr = lane & 15, fg = lane >> 4;
    const float scale = 0.07216878364870322f;  // 1/sqrt(192)
    const bf16* Kbase = Kb + (size_t)h * N_TOK * QKH;
    const bf16* Vbase = Vt + (size_t)h * VH * N_TOK;

    for (int pi = 0; pi < 2; ++pi) {
        int qp = pi ? 63 - yp : yp;
        bf16x8 aq[6];
        const bf16* Qsrc = qb + ((size_t)h * N_TOK + qp * 32 + w * 16) * QKH;
#pragma unroll
        for (int ks = 0; ks < 6; ++ks)
            aq[ks] = *(const bf16x8*)(Qsrc + (size_t)fr * QKH + ks * 32 + fg * 8);

        f32x4 acc_o[8] = {};
        float m_r[4], l_r[4];
#pragma unroll
        for (int q = 0; q < 4; ++q) { m_r[q] = -1e30f; l_r[q] = 0.f; }

        int nkt = (qp >> 1) + 1;
        for (int kt = 0; kt < nkt; ++kt) {
            __syncthreads();
            {
                const bf16* Ksrc = Kbase + (size_t)kt * 64 * QKH;
#pragma unroll
                for (int c = 0; c < 12; ++c) {
                    int idx = c * 128 + t;
                    int row = idx / 24, c16 = idx - row * 24;
                    int4 v = *(const int4*)(Ksrc + row * QKH + c16 * 8);
                    *(int4*)(Ks + row * 200 + c16 * 8) = v;
                }
                const bf16* Vsrc = Vbase + kt * 64;
#pragma unroll
                for (int c = 0; c < 8; ++c) {
                    int idx = c * 128 + t;
                    int row = idx >> 3, c8 = idx & 7;
                    int4 v = *(const int4*)(Vsrc + (size_t)row * N_TOK + c8 * 8);
                    *(int4*)(Vs + row * 72 + c8 * 8) = v;
                }
            }
            __syncthreads();
            f32x4 acc_s[4] = {};
#pragma unroll
            for (int ks = 0; ks < 6; ++ks) {
                bf16x8 bv[4];
#pragma unroll
                for (int j = 0; j < 4; ++j)
                    bv[j] = *(const bf16x8*)(Ks + (j * 16 + fr) * 200 + ks * 32 + fg * 8);
#pragma unroll
                for (int j = 0; j < 4; ++j)
                    acc_s[j] = __builtin_amdgcn_mfma_f32_16x16x32_bf16(aq[ks], bv[j], acc_s[j], 0, 0, 0);
            }
            if (kt == nkt - 1) {
                int colb = kt * 64;
                int rowb = qp * 32 + w * 16;
#pragma unroll
                for (int j = 0; j < 4; ++j)
#pragma unroll
                    for (int q = 0; q < 4; ++q)
                        if (colb + j * 16 + fr > rowb + fg * 4 + q)
                            acc_s[j][q] = -1e30f;
            }
#pragma unroll
            for (int q = 0; q < 4; ++q) {
                float tmax = fmaxf(fmaxf(acc_s[0][q], acc_s[1][q]),
                                   fmaxf(acc_s[2][q], acc_s[3][q]));
                tmax = fmaxf(tmax, __shfl_xor(tmax, 1, 64));
                tmax = fmaxf(tmax, __shfl_xor(tmax, 2, 64));
                tmax = fmaxf(tmax, __shfl_xor(tmax, 4, 64));
                tmax = fmaxf(tmax, __shfl_xor(tmax, 8, 64));
                float mn = fmaxf(m_r[q], tmax);
                float sc = __expf(scale * (m_r[q] - mn));
                m_r[q] = mn;
                float s0 = 0.f;
#pragma unroll
                for (int j = 0; j < 4; ++j) {
                    float pv = __expf(scale * (acc_s[j][q] - mn));
                    acc_s[j][q] = pv;
                    s0 += pv;
                }
                s0 += __shfl_xor(s0, 1, 64);
                s0 += __shfl_xor(s0, 2, 64);
                s0 += __shfl_xor(s0, 4, 64);
                s0 += __shfl_xor(s0, 8, 64);
                l_r[q] = l_r[q] * sc + s0;
#pragma unroll
                for (int jo = 0; jo < 8; ++jo) acc_o[jo][q] *= sc;
            }
#pragma unroll
            for (int j = 0; j < 4; ++j)
#pragma unroll
                for (int q = 0; q < 4; ++q)
                    Ps[(w * 16 + fg * 4 + q) * 72 + j * 16 + fr] = (short)f2bfu(acc_s[j][q]);
#pragma unroll
            for (int ks2 = 0; ks2 < 2; ++ks2) {
                bf16x8 pa = *(const bf16x8*)(Ps + (w * 16 + fr) * 72 + ks2 * 32 + fg * 8);
#pragma unroll
                for (int jo = 0; jo < 8; ++jo) {
                    bf16x8 vb = *(const bf16x8*)(Vs + (jo * 16 + fr) * 72 + ks2 * 32 + fg * 8);
                    acc_o[jo] = __builtin_amdgcn_mfma_f32_16x16x32_bf16(pa, vb, acc_o[jo], 0, 0, 0);
                }
            }
        }
        bf16* obase = aout + (size_t)(qp * 32 + w * 16) * (NH * VH) + h * VH;
#pragma unroll
        for (int q = 0; q < 4; ++q) {
            float inv = 1.f / l_r[q];
#pragma unroll
            for (int jo = 0; jo < 8; ++jo)
                obase[(size_t)(fg * 4 + q) * (NH * VH) + jo * 16 + fr] =
                    __float2bfloat16(acc_o[jo][q] * inv);
        }
    }
}

extern "C" void kernel_launch(void* const* d_in, const int* in_sizes, int n_in,
                              void* d_out, int out_size, void* d_ws, size_t ws_size,
                              hipStream_t stream) {
    (void)in_sizes; (void)n_in; (void)out_size;
    const int* tokens = (const int*)d_in[0];
    const float* emb = (const float*)d_in[1];
    const float* qW = (const float*)d_in[2];
    const float* kvaW = (const float*)d_in[3];
    const float* kvnorm_w = (const float*)d_in[4];
    const float* kvbW = (const float*)d_in[5];
    const float* oW = (const float*)d_in[6];
    const float* w1 = (const float*)d_in[7];
    const float* w2 = (const float*)d_in[8];
    const float* w3 = (const float*)d_in[9];
    const float* attn_norm_w = (const float*)d_in[10];
    const float* ffn_norm_w = (const float*)d_in[11];
    const float* norm_w = (const float*)d_in[12];
    const float* outW = (const float*)d_in[13];
    const float* rope_cos = (const float*)d_in[14];
    const float* rope_sin = (const float*)d_in[15];

    hipFuncSetAttribute((const void*)k_mm<0>, hipFuncAttributeMaxDynamicSharedMemorySize, 65536);
    hipFuncSetAttribute((const void*)k_mm<1>, hipFuncAttributeMaxDynamicSharedMemorySize, 65536);
    hipFuncSetAttribute((const void*)k_mm<3>, hipFuncAttributeMaxDynamicSharedMemorySize, 65536);
    hipFuncSetAttribute((const void*)k_mm<4>, hipFuncAttributeMaxDynamicSharedMemorySize, 65536);

    float* ws = (float*)d_ws;
    size_t off = 0;
    auto allocF = [&](size_t fl) { float* p = ws + off; off += (fl + 63) & ~63ULL; return p; };
    float* h    = allocF(4194304);            // [2048][2048] f32
    bf16* xb    = (bf16*)allocF(2097152);     // [2048][2048] bf16
    bf16* cb    = (bf16*)allocF(524288);      // [2048][512] bf16
    bf16* qb    = (bf16*)allocF(3145728);     // [16][2048][192] bf16
    bf16* Kb    = (bf16*)allocF(3145728);     // [16][2048][192] bf16
    bf16* Vt    = (bf16*)allocF(2097152);     // [16][128][2048] bf16
    bf16* aout  = (bf16*)allocF(2097152);     // [2048][2048] bf16
    bf16* qWt   = (bf16*)allocF(3145728);     // [3072][2048]
    bf16* kvaWt = (bf16*)allocF(655360);      // [640][2048]
    bf16* kvbWt = (bf16*)allocF(1048576);     // [4096][512]
    bf16* oWt   = (bf16*)allocF(2097152);     // [2048][2048]
    bf16* w12t  = (bf16*)allocF(11534336);    // [11264][2048] interleaved w1/w2
    bf16* w3t   = (bf16*)allocF(5767168);     // [2048][5632]
    float* scr  = ws + off;
    size_t availF = (ws_size / 4 > off) ? ws_size / 4 - off : 0;

    int oc = 25;
    {
        const int ocs[3] = {1, 5, 25};
        for (int i = 0; i < 3; ++i) {
            size_t need = 7602176;                         // qkv [2048][3712] f32
            size_t a2 = (size_t)32768000 / ocs[i];         // outW chunk (bf16, in floats)
            if (a2 > need) need = a2;
            if (5767168 > need) need = 5767168;            // fbig [2048][5632] bf16
            if (need <= availF) { oc = ocs[i]; break; }
        }
    }
    float* qkv  = scr;                          // [2048][3712] f32 (dead after qpack)
    bf16* fbig  = (bf16*)scr;                   // [2048][5632] bf16
    bf16* oWtc  = (bf16*)scr;                   // outW chunk [cn][2048]

    k_embed<<<N_TOK, 256, 0, stream>>>(tokens, emb, h);

    for (int l = 0; l < NLAYER; ++l) {
        ConvBatch cbt;
        const float* srcs[7] = {qW + (size_t)l * DIM * 3072, kvaW + (size_t)l * DIM * 576,
                                kvbW + (size_t)l * 512 * 4096, oW + (size_t)l * 2048 * 2048,
                                w1 + (size_t)l * DIM * INTER, w2 + (size_t)l * DIM * INTER,
                                w3 + (size_t)l * INTER * DIM};
        bf16* dsts[7]  = {qWt, kvaWt, kvbWt, oWt, w12t, w12t, w3t};
        int Ks[7]   = {2048, 2048, 512, 2048, 2048, 2048, 5632};
        int ldws[7] = {3072, 576, 4096, 2048, 5632, 5632, 2048};
        int ncs[7]  = {3072, 576, 4096, 2048, 5632, 5632, 2048};
        int ilvs[7] = {-1, -1, -1, -1, 0, 16, -1};
        int nbxs[7] = {48, 10, 64, 32, 88, 88, 32};
        int nbys[7] = {64, 64, 16, 64, 64, 64, 176};
        int tot = 0;
        for (int i = 0; i < 7; ++i) {
            cbt.W[i] = srcs[i]; cbt.Out[i] = dsts[i];
            cbt.K[i] = Ks[i]; cbt.ldw[i] = ldws[i]; cbt.ncols[i] = ncs[i];
            cbt.ilv[i] = ilvs[i]; cbt.nbx[i] = nbxs[i];
            cbt.blk0[i] = tot; tot += nbxs[i] * nbys[i];
        }
        cbt.blk0[7] = tot;
        k_convAll<<<dim3(tot), 256, 0, stream>>>(cbt);

        k_rmsnorm<<<N_TOK, 256, 0, stream>>>(h, 2048, 0, xb, attn_norm_w + (size_t)l * DIM, 2048);
        // merged q + kva projection: N = 3072 + 640 = 3712
        k_mm<0><<<dim3(464), 256, 65536, stream>>>(xb, qWt, qkv, nullptr, 3712, 2048, 2048, 2048, 3712);
        k_qpack<<<N_TOK, 256, 0, stream>>>(qkv, 3712, 3072, rope_cos, rope_sin, qb, Kb,
                                           kvnorm_w + (size_t)l * KVR, cb);
        // qkv now dead; kvb GEMM writes Kb-nope + Vt (transposed) directly (OUT=4)
        k_mm<4><<<dim3(512), 256, 65536, stream>>>(cb, kvbWt, Kb, Vt, 4096, 512, 512, 512, 0);
        k_flash<<<dim3(NH, 32), 128, 0, stream>>>(qb, Kb, Vt, aout);
        k_mm<1><<<dim3(256), 256, 65536, stream>>>(aout, oWt, h, nullptr, 2048, 2048, 2048, 2048, 2048);

        k_rmsnorm<<<N_TOK, 256, 0, stream>>>(h, 2048, 0, xb, ffn_norm_w + (size_t)l * DIM, 2048);
        // merged w1+w2 (interleaved ilv=16) with fused silu epilogue -> fbig [2048][5632] bf16
        k_mm<3><<<dim3(1408), 256, 65536, stream>>>(xb, w12t, fbig, nullptr, 11264, 2048, 2048, 2048, 5632);
        k_mm<1><<<dim3(256), 256, 65536, stream>>>(fbig, w3t, h, nullptr, 2048, 5632, 5632, 5632, 2048);
    }
    k_rmsnorm<<<N_TOK, 256, 0, stream>>>(h, 2048, 0, xb, norm_w, 2048);
    int cn = 32000 / oc;
    for (int c2 = 0; c2 < oc; ++c2) {
        k_convT<<<dim3(cn / 64, 64), 256, 0, stream>>>(outW, oWtc, 2048, 32000, cn, c2 * cn, -1);
        k_mm<0><<<dim3(16 * (cn / 128)), 256, 65536, stream>>>(
            xb, oWtc, (float*)d_out + (size_t)c2 * cn, nullptr, cn, 2048, 2048, 2048, 32000);
    }
}

// Round 16
// 1262.939 us; speedup vs baseline: 1.0992x; 1.0992x over previous
//
#include <hip/hip_runtime.h>
#include <hip/hip_bf16.h>
#include <math.h>

#define N_TOK 2048
#define DIM   2048
#define NH    16
#define NOPE  128
#define ROPE_D 64
#define QKH   192
#define VH    128
#define KVR   512
#define INTER 5632
#define VOCAB 32000
#define NLAYER 2
#define EPS   1e-6f

typedef __hip_bfloat16 bf16;
typedef __bf16 bf16x8 __attribute__((ext_vector_type(8)));
typedef float  f32x4  __attribute__((ext_vector_type(4)));

__device__ __forceinline__ float bf2f(unsigned short u) {
    union { unsigned u; float f; } a; a.u = ((unsigned)u) << 16; return a.f;
}
__device__ __forceinline__ unsigned short f2bfu(float f) {
    union { float f; unsigned u; } a; a.f = f;
    return (unsigned short)((a.u + 0x7fffu + ((a.u >> 16) & 1u)) >> 16);
}

__device__ __forceinline__ void gload16(const void* g, void* l) {
    __builtin_amdgcn_global_load_lds((const __attribute__((address_space(1))) void*)g,
                                     (__attribute__((address_space(3))) void*)l, 16, 0, 0);
}

// ---------------- embedding gather ----------------
__global__ void k_embed(const int* __restrict__ tokens, const float* __restrict__ emb,
                        float* __restrict__ h) {
    int n = blockIdx.x;
    int t = tokens[n];
    const float4* src = (const float4*)(emb + (size_t)t * DIM);
    float4* dst = (float4*)(h + (size_t)n * DIM);
    for (int i = threadIdx.x; i < DIM / 4; i += blockDim.x) dst[i] = src[i];
}

// ---------------- rmsnorm f32 -> bf16 ----------------
__global__ __launch_bounds__(256) void k_rmsnorm(const float* __restrict__ in, int in_stride, int in_off,
                                                 bf16* __restrict__ out, const float* __restrict__ w,
                                                 int len) {
    int row = blockIdx.x;
    const float* x = in + (size_t)row * in_stride + in_off;
    float ss = 0.f;
    for (int i = threadIdx.x; i < len; i += 256) { float v = x[i]; ss += v * v; }
    for (int off = 32; off > 0; off >>= 1) ss += __shfl_down(ss, off, 64);
    __shared__ float red[4];
    if ((threadIdx.x & 63) == 0) red[threadIdx.x >> 6] = ss;
    __syncthreads();
    float tot = red[0] + red[1] + red[2] + red[3];
    float inv = rsqrtf(tot / (float)len + EPS);
    for (int i = threadIdx.x; i < len; i += 256)
        out[(size_t)row * len + i] = __float2bfloat16(x[i] * inv * w[i]);
}

// ---------------- conv body: W[K][ncols] f32 (col base c0) -> Out bf16 [n][K] ----------------
__device__ __forceinline__ void conv_body(const float* __restrict__ W, bf16* __restrict__ Out,
                                          int K, int ldw, int ncols, int c0, int ilv,
                                          int bx, int by) {
    __shared__ float T[32][65];
    int n0 = bx * 64, k0 = by * 32;
    int tid = threadIdx.x;
    int rr = tid >> 4, cc = (tid & 15) * 4;
#pragma unroll
    for (int p = 0; p < 2; ++p) {
        int k = k0 + rr + p * 16;
        float4 v = make_float4(0.f, 0.f, 0.f, 0.f);
        if (n0 + cc < ncols) v = *(const float4*)(W + (size_t)k * ldw + c0 + n0 + cc);
        T[rr + p * 16][cc + 0] = v.x; T[rr + p * 16][cc + 1] = v.y;
        T[rr + p * 16][cc + 2] = v.z; T[rr + p * 16][cc + 3] = v.w;
    }
    __syncthreads();
    int n = tid >> 2, kc = (tid & 3) * 8;
    __align__(16) bf16 tmp[8];
#pragma unroll
    for (int e = 0; e < 8; ++e) tmp[e] = __float2bfloat16(T[kc + e][n]);
    int nl = n0 + n;
    int prow = (ilv < 0) ? nl : (((nl >> 4) << 5) + (nl & 15) + ilv);
    *(int4*)(Out + (size_t)prow * K + k0 + kc) = *(const int4*)tmp;
}

__global__ __launch_bounds__(256)
void k_convT(const float* __restrict__ W, bf16* __restrict__ Out,
             int K, int ldw, int ncols, int c0, int ilv) {
    conv_body(W, Out, K, ldw, ncols, c0, ilv, blockIdx.x, blockIdx.y);
}

// ---------------- batched weight conversion ----------------
struct ConvBatch {
    const float* W[7];
    bf16* Out[7];
    int K[7], ldw[7], ncols[7], ilv[7], nbx[7];
    int blk0[8];
};

__global__ __launch_bounds__(256) void k_convAll(ConvBatch cb) {
    int bid = blockIdx.x;
    int seg = 0;
#pragma unroll
    for (int i = 1; i < 7; ++i) if (bid >= cb.blk0[i]) seg = i;
    int rem = bid - cb.blk0[seg];
    int bx = rem % cb.nbx[seg], by = rem / cb.nbx[seg];
    conv_body(cb.W[seg], cb.Out[seg], cb.K[seg], cb.ldw[seg], cb.ncols[seg], 0, cb.ilv[seg],
              bx, by);
}

// ---------------- bf16 MFMA GEMM, 128x128 tile, ring-4 LDS, counted vmcnt ----------------
// OUT: 0=f32 store, 1=f32 +=, 4=split pack (Cv=Kb nope, Cv2=Vt [h][d][key] direct).
#define TILE4(u, DOSTAGE, GATE) { \
    const int t = t0 + (u); \
    const bf16* sAb = sA_ + (u) * 4096; \
    const bf16* sBb = sB_ + (u) * 4096; \
    bf16* dA = sA_ + (((u) + 3) & 3) * 4096; \
    bf16* dB = sB_ + (((u) + 3) & 3) * 4096; \
    if (DOSTAGE) { \
        size_t kk = (size_t)(t + 3) * 32; \
        gload16(A + (size_t)(row0 + srow) * lda + kk + scol * 8, dA + tid * 8); \
        gload16(A + (size_t)(row0 + 64 + srow) * lda + kk + scol * 8, dA + 2048 + tid * 8); \
    } \
    bf16x8 av0[2], bv[4]; \
    _Pragma("unroll") \
    for (int m = 0; m < 2; ++m) \
        av0[m] = *(const bf16x8*)(sAb + (wm + m * 16 + fr) * 32 + swz); \
    _Pragma("unroll") \
    for (int n = 0; n < 4; ++n) \
        bv[n] = *(const bf16x8*)(sBb + (wn + n * 16 + fr) * 32 + swz); \
    __builtin_amdgcn_s_barrier(); \
    __builtin_amdgcn_s_setprio(1); \
    _Pragma("unroll") \
    for (int m = 0; m < 2; ++m) { \
        acc[m][0] = __builtin_amdgcn_mfma_f32_16x16x32_bf16(av0[m], bv[0], acc[m][0], 0, 0, 0); \
        acc[m][1] = __builtin_amdgcn_mfma_f32_16x16x32_bf16(av0[m], bv[1], acc[m][1], 0, 0, 0); \
        acc[m][2] = __builtin_amdgcn_mfma_f32_16x16x32_bf16(av0[m], bv[2], acc[m][2], 0, 0, 0); \
        acc[m][3] = __builtin_amdgcn_mfma_f32_16x16x32_bf16(av0[m], bv[3], acc[m][3], 0, 0, 0); \
    } \
    __builtin_amdgcn_s_setprio(0); \
    __builtin_amdgcn_s_barrier(); \
    if (DOSTAGE) { \
        size_t kk = (size_t)(t + 3) * 32; \
        gload16(Bt + (size_t)(col0 + srow) * ldb + kk + scol * 8, dB + tid * 8); \
        gload16(Bt + (size_t)(col0 + 64 + srow) * ldb + kk + scol * 8, dB + 2048 + tid * 8); \
    } \
    bf16x8 av1[2]; \
    _Pragma("unroll") \
    for (int m = 0; m < 2; ++m) \
        av1[m] = *(const bf16x8*)(sAb + (wm + (m + 2) * 16 + fr) * 32 + swz); \
    __builtin_amdgcn_s_barrier(); \
    __builtin_amdgcn_s_setprio(1); \
    _Pragma("unroll") \
    for (int m = 0; m < 2; ++m) { \
        acc[m + 2][0] = __builtin_amdgcn_mfma_f32_16x16x32_bf16(av1[m], bv[0], acc[m + 2][0], 0, 0, 0); \
        acc[m + 2][1] = __builtin_amdgcn_mfma_f32_16x16x32_bf16(av1[m], bv[1], acc[m + 2][1], 0, 0, 0); \
        acc[m + 2][2] = __builtin_amdgcn_mfma_f32_16x16x32_bf16(av1[m], bv[2], acc[m + 2][2], 0, 0, 0); \
        acc[m + 2][3] = __builtin_amdgcn_mfma_f32_16x16x32_bf16(av1[m], bv[3], acc[m + 2][3], 0, 0, 0); \
    } \
    __builtin_amdgcn_s_setprio(0); \
    GATE; \
    __builtin_amdgcn_s_barrier(); \
    __builtin_amdgcn_sched_barrier(0); \
}

template<int OUT>
__global__ __launch_bounds__(256, 2)
void k_mm(const bf16* __restrict__ A, const bf16* __restrict__ Bt, void* __restrict__ Cv,
          void* __restrict__ Cv2, int Nreal, int K, int lda, int ldb, int ldc) {
    extern __shared__ char smem_raw[];
    bf16* sA_ = (bf16*)smem_raw;            // 4 bufs x 128x32
    bf16* sB_ = sA_ + 4 * 4096;
    int cpx = gridDim.x >> 3;
    int logical = ((int)blockIdx.x & 7) * cpx + ((int)blockIdx.x >> 3);
    int row0 = (logical & 15) * 128, col0 = (logical >> 4) * 128;
    int tid = threadIdx.x;
    int lane = tid & 63, wave = tid >> 6;
    int wm = (wave & 1) * 64, wn = (wave >> 1) * 64;
    int fr = lane & 15, fg = lane >> 4;
    int srow = tid >> 2;
    int scol = (tid & 3) ^ ((srow >> 1) & 3);            // T2 staging source slot
    int swz = (fg ^ ((fr >> 1) & 3)) * 8;                // T2 read slot (elem offset)

    f32x4 acc[4][4] = {};
    int nt = K >> 5;

#pragma unroll
    for (int t = 0; t < 3; ++t) {
        size_t kk = (size_t)t * 32;
        bf16* dA = sA_ + t * 4096;
        bf16* dB = sB_ + t * 4096;
        gload16(A + (size_t)(row0 + srow) * lda + kk + scol * 8, dA + tid * 8);
        gload16(A + (size_t)(row0 + 64 + srow) * lda + kk + scol * 8, dA + 2048 + tid * 8);
        gload16(Bt + (size_t)(col0 + srow) * ldb + kk + scol * 8, dB + tid * 8);
        gload16(Bt + (size_t)(col0 + 64 + srow) * ldb + kk + scol * 8, dB + 2048 + tid * 8);
    }
    asm volatile("s_waitcnt vmcnt(8)" ::: "memory");
    __builtin_amdgcn_s_barrier();
    __builtin_amdgcn_sched_barrier(0);

    int ngroups = nt >> 2;
    for (int g = 0; g < ngroups - 1; ++g) {
        int t0 = g * 4;
        TILE4(0, 1, asm volatile("s_waitcnt vmcnt(8)" ::: "memory"));
        TILE4(1, 1, asm volatile("s_waitcnt vmcnt(8)" ::: "memory"));
        TILE4(2, 1, asm volatile("s_waitcnt vmcnt(8)" ::: "memory"));
        TILE4(3, 1, asm volatile("s_waitcnt vmcnt(8)" ::: "memory"));
    }
    {
        int t0 = nt - 4;
        TILE4(0, 1, asm volatile("s_waitcnt vmcnt(8)" ::: "memory"));
        TILE4(1, 0, asm volatile("s_waitcnt vmcnt(4)" ::: "memory"));
        TILE4(2, 0, asm volatile("s_waitcnt vmcnt(0)" ::: "memory"));
        TILE4(3, 0, (void)0);
    }

    float* Cf = (float*)Cv;
    bf16* Cb = (bf16*)Cv;
    bf16* Vtp = (bf16*)Cv2;
#pragma unroll
    for (int i = 0; i < 4; ++i)
#pragma unroll
        for (int j = 0; j < 4; ++j)
#pragma unroll
            for (int q = 0; q < 4; ++q) {
                int row = row0 + wm + i * 16 + fg * 4 + q;
                int col = col0 + wn + j * 16 + fr;
                if (col < Nreal) {
                    if (OUT == 0) Cf[(size_t)row * ldc + col] = acc[i][j][q];
                    else if (OUT == 1) Cf[(size_t)row * ldc + col] += acc[i][j][q];
                    else {  // OUT == 4: kvb pack (K-nope + V transposed directly)
                        int head = col >> 8, d = col & 255;
                        if (d < NOPE)
                            Cb[(size_t)head * N_TOK * QKH + (size_t)row * QKH + d] =
                                __float2bfloat16(acc[i][j][q]);
                        else
                            Vtp[(size_t)head * VH * N_TOK + (size_t)(d - NOPE) * N_TOK + row] =
                                __float2bfloat16(acc[i][j][q]);
                    }
                }
            }
}

// ---------------- bf16 MFMA GEMM, 256x256 tile, BK=32, ring-4 LDS ----------------
#define TILE8(u, DOSTAGE, GATE) { \
    const int t = t0 + (u); \
    const bf16* sAb = sA_ + (u) * 8192; \
    const bf16* sBb = sB_ + (u) * 8192; \
    bf16* dA = sA_ + (((u) + 3) & 3) * 8192; \
    bf16* dB = sB_ + (((u) + 3) & 3) * 8192; \
    if (DOSTAGE) { \
        size_t kk = (size_t)(t + 3) * 32; \
        gload16(Ag + (size_t)(row0 + srow) * lda + kk + scol * 8, dA + tid * 8); \
        gload16(Ag + (size_t)(row0 + 128 + srow) * lda + kk + scol * 8, dA + 4096 + tid * 8); \
    } \
    bf16x8 av0[4], bv[4]; \
    _Pragma("unroll") \
    for (int m = 0; m < 4; ++m) \
        av0[m] = *(const bf16x8*)(sAb + (wm * 128 + m * 16 + fr) * 32 + swz); \
    _Pragma("unroll") \
    for (int n = 0; n < 4; ++n) \
        bv[n] = *(const bf16x8*)(sBb + (wn * 64 + n * 16 + fr) * 32 + swz); \
    __builtin_amdgcn_s_barrier(); \
    __builtin_amdgcn_s_setprio(1); \
    _Pragma("unroll") \
    for (int m = 0; m < 4; ++m) { \
        acc[m][0] = __builtin_amdgcn_mfma_f32_16x16x32_bf16(av0[m], bv[0], acc[m][0], 0, 0, 0); \
        acc[m][1] = __builtin_amdgcn_mfma_f32_16x16x32_bf16(av0[m], bv[1], acc[m][1], 0, 0, 0); \
        acc[m][2] = __builtin_amdgcn_mfma_f32_16x16x32_bf16(av0[m], bv[2], acc[m][2], 0, 0, 0); \
        acc[m][3] = __builtin_amdgcn_mfma_f32_16x16x32_bf16(av0[m], bv[3], acc[m][3], 0, 0, 0); \
    } \
    __builtin_amdgcn_s_setprio(0); \
    __builtin_amdgcn_s_barrier(); \
    if (DOSTAGE) { \
        size_t kk = (size_t)(t + 3) * 32; \
        gload16(Bg + (size_t)(col0 + srow) * ldb + kk + scol * 8, dB + tid * 8); \
        gload16(Bg + (size_t)(col0 + 128 + srow) * ldb + kk + scol * 8, dB + 4096 + tid * 8); \
    } \
    bf16x8 av1[4]; \
    _Pragma("unroll") \
    for (int m = 0; m < 4; ++m) \
        av1[m] = *(const bf16x8*)(sAb + (wm * 128 + (m + 4) * 16 + fr) * 32 + swz); \
    __builtin_amdgcn_s_barrier(); \
    __builtin_amdgcn_s_setprio(1); \
    _Pragma("unroll") \
    for (int m = 0; m < 4; ++m) { \
        acc[m + 4][0] = __builtin_amdgcn_mfma_f32_16x16x32_bf16(av1[m], bv[0], acc[m + 4][0], 0, 0, 0); \
        acc[m + 4][1] = __builtin_amdgcn_mfma_f32_16x16x32_bf16(av1[m], bv[1], acc[m + 4][1], 0, 0, 0); \
        acc[m + 4][2] = __builtin_amdgcn_mfma_f32_16x16x32_bf16(av1[m], bv[2], acc[m + 4][2], 0, 0, 0); \
        acc[m + 4][3] = __builtin_amdgcn_mfma_f32_16x16x32_bf16(av1[m], bv[3], acc[m + 4][3], 0, 0, 0); \
    } \
    __builtin_amdgcn_s_setprio(0); \
    GATE; \
    __builtin_amdgcn_s_barrier(); \
    __builtin_amdgcn_sched_barrier(0); \
}

// OUT: 0 = f32 store (ldc), 3 = fused silu on interleaved w1w2 -> bf16 [M][5632]
template<int OUT>
__global__ __launch_bounds__(512, 2)
void k_mm8(const bf16* __restrict__ Ag, const bf16* __restrict__ Bg, void* __restrict__ Cv,
           int K, int lda, int ldb, int ldc) {
    extern __shared__ char smem_raw[];
    bf16* sA_ = (bf16*)smem_raw;            // 4 bufs x 256x32
    bf16* sB_ = sA_ + 4 * 8192;
    int tid = threadIdx.x;
    int lane = tid & 63, wid = tid >> 6;
    int wm = wid >> 2, wn = wid & 3;        // 2 x 4 waves, wave tile 128x64
    int fr = lane & 15, fg = lane >> 4;
    int cpx = gridDim.x >> 3;
    int logical = ((int)blockIdx.x & 7) * cpx + ((int)blockIdx.x >> 3);
    int row0 = (logical & 7) * 256, col0 = (logical >> 3) * 256;
    int srow = tid >> 2;
    int scol = (tid & 3) ^ ((srow >> 1) & 3);
    int swz = (fg ^ ((fr >> 1) & 3)) * 8;

    f32x4 acc[8][4] = {};
    int nt = K >> 5;

#pragma unroll
    for (int t = 0; t < 3; ++t) {
        size_t kk = (size_t)t * 32;
        bf16* dA = sA_ + t * 8192;
        bf16* dB = sB_ + t * 8192;
        gload16(Ag + (size_t)(row0 + srow) * lda + kk + scol * 8, dA + tid * 8);
        gload16(Ag + (size_t)(row0 + 128 + srow) * lda + kk + scol * 8, dA + 4096 + tid * 8);
        gload16(Bg + (size_t)(col0 + srow) * ldb + kk + scol * 8, dB + tid * 8);
        gload16(Bg + (size_t)(col0 + 128 + srow) * ldb + kk + scol * 8, dB + 4096 + tid * 8);
    }
    asm volatile("s_waitcnt vmcnt(8)" ::: "memory");
    __builtin_amdgcn_s_barrier();
    __builtin_amdgcn_sched_barrier(0);

    int ngroups = nt >> 2;
    for (int g = 0; g < ngroups - 1; ++g) {
        int t0 = g * 4;
        TILE8(0, 1, asm volatile("s_waitcnt vmcnt(8)" ::: "memory"));
        TILE8(1, 1, asm volatile("s_waitcnt vmcnt(8)" ::: "memory"));
        TILE8(2, 1, asm volatile("s_waitcnt vmcnt(8)" ::: "memory"));
        TILE8(3, 1, asm volatile("s_waitcnt vmcnt(8)" ::: "memory"));
    }
    {
        int t0 = nt - 4;
        TILE8(0, 1, asm volatile("s_waitcnt vmcnt(8)" ::: "memory"));
        TILE8(1, 0, asm volatile("s_waitcnt vmcnt(4)" ::: "memory"));
        TILE8(2, 0, asm volatile("s_waitcnt vmcnt(0)" ::: "memory"));
        TILE8(3, 0, (void)0);
    }

    if (OUT == 0) {
        float* Cf = (float*)Cv;
#pragma unroll
        for (int m = 0; m < 8; ++m)
#pragma unroll
            for (int n = 0; n < 4; ++n)
#pragma unroll
                for (int q = 0; q < 4; ++q) {
                    int row = row0 + wm * 128 + m * 16 + fg * 4 + q;
                    int col = col0 + wn * 64 + n * 16 + fr;
                    Cf[(size_t)row * ldc + col] = acc[m][n][q];
                }
    } else {  // OUT == 3: silu(w1)*w2 fused
        bf16* Cb = (bf16*)Cv;
#pragma unroll
        for (int m = 0; m < 8; ++m)
#pragma unroll
            for (int p2 = 0; p2 < 2; ++p2)
#pragma unroll
                for (int q = 0; q < 4; ++q) {
                    int row = row0 + wm * 128 + m * 16 + fg * 4 + q;
                    int col = (col0 >> 1) + wn * 32 + p2 * 16 + fr;
                    float a = acc[m][2 * p2][q], b = acc[m][2 * p2 + 1][q];
                    float r = a / (1.f + __expf(-a)) * b;
                    Cb[(size_t)row * ldc + col] = __float2bfloat16(r);
                }
    }
}

// ---------------- q rope+pack (scale folded), Kb rope broadcast, kv rmsnorm -> cb ----------------
__global__ __launch_bounds__(256) void k_qpack(const float* __restrict__ q, int qstride, int kvoff,
        const float* __restrict__ cosb, const float* __restrict__ sinb,
        bf16* __restrict__ qb, bf16* __restrict__ Kb,
        const float* __restrict__ kvnw, bf16* __restrict__ cb) {
    int n = blockIdx.x;
    const float scale = 0.07216878364870322f;  // 1/sqrt(192), folded into qb
    __shared__ float c[32], s[32];
    __shared__ float red[4];
    if (threadIdx.x < 32) {
        c[threadIdx.x] = cosb[n * 32 + threadIdx.x];
        s[threadIdx.x] = sinb[n * 32 + threadIdx.x];
    }
    __syncthreads();
    const float* row = q + (size_t)n * qstride;
    {
        float ss = 0.f;
        for (int i = threadIdx.x; i < KVR; i += 256) {
            float v = row[kvoff + 64 + i]; ss += v * v;
        }
        for (int off = 32; off > 0; off >>= 1) ss += __shfl_down(ss, off, 64);
        if ((threadIdx.x & 63) == 0) red[threadIdx.x >> 6] = ss;
        __syncthreads();
        float inv = rsqrtf((red[0] + red[1] + red[2] + red[3]) / (float)KVR + EPS);
        for (int i = threadIdx.x; i < KVR; i += 256)
            cb[(size_t)n * KVR + i] = __float2bfloat16(row[kvoff + 64 + i] * inv * kvnw[i]);
    }
    if (threadIdx.x < 32) {
        int i = threadIdx.x;
        float xr = row[kvoff + 2 * i], xi = row[kvoff + 2 * i + 1];
        float r0 = xr * c[i] - xi * s[i];
        float r1 = xr * s[i] + xi * c[i];
        unsigned pk = (unsigned)f2bfu(r0) | ((unsigned)f2bfu(r1) << 16);
#pragma unroll
        for (int hh = 0; hh < NH; ++hh)
            *(unsigned*)(Kb + (size_t)hh * N_TOK * QKH + (size_t)n * QKH + NOPE + 2 * i) = pk;
    }
    for (int idx = threadIdx.x; idx < NH * QKH; idx += 256) {
        int h = idx / QKH, d = idx - h * QKH;
        float v;
        if (d < NOPE) v = row[idx];
        else {
            int i = (d - NOPE) >> 1;
            float xr = row[h * QKH + NOPE + 2 * i], xi = row[h * QKH + NOPE + 2 * i + 1];
            v = ((d & 1) == 0) ? xr * c[i] - xi * s[i] : xr * s[i] + xi * c[i];
        }
        qb[(size_t)h * (N_TOK * QKH) + (size_t)n * QKH + d] = __float2bfloat16(v * scale);
    }
}

// ---------------- fused flash attention, QBLK=32, 2 waves, paired panels ----------------
__global__ __launch_bounds__(128, 2)
void k_flash(const bf16* __restrict__ qb, const bf16* __restrict__ Kb,
             const bf16* __restrict__ Vt, bf16* __restrict__ aout) {
    int h = blockIdx.x, yp = blockIdx.y;
    __shared__ short Ks[64 * 200];
    __shared__ short Vs[128 * 72];
    __shared__ short Ps[32 * 72];
    int t = threadIdx.x;
    int lane = t & 63, w = t >> 6;
    int fr = lane & 15, fg = lane >> 4;
    const bf16* Kbase = Kb + (size_t)h * N_TOK * QKH;
    const bf16* Vbase = Vt + (size_t)h * VH * N_TOK;

    for (int pi = 0; pi < 2; ++pi) {
        int qp = pi ? 63 - yp : yp;
        bf16x8 aq[6];
        const bf16* Qsrc = qb + ((size_t)h * N_TOK + qp * 32 + w * 16) * QKH;
#pragma unroll
        for (int ks = 0; ks < 6; ++ks)
            aq[ks] = *(const bf16x8*)(Qsrc + (size_t)fr * QKH + ks * 32 + fg * 8);

        f32x4 acc_o[8] = {};
        float m_r[4], l_r[4];
#pragma unroll
        for (int q = 0; q < 4; ++q) { m_r[q] = -1e30f; l_r[q] = 0.f; }

        int nkt = (qp >> 1) + 1;
        for (int kt = 0; kt < nkt; ++kt) {
            __syncthreads();
            {
                const bf16* Ksrc = Kbase + (size_t)kt * 64 * QKH;
#pragma unroll
                for (int c = 0; c < 12; ++c) {
                    int idx = c * 128 + t;
                    int row = idx / 24, c16 = idx - row * 24;
                    int4 v = *(const int4*)(Ksrc + row * QKH + c16 * 8);
                    *(int4*)(Ks + row * 200 + c16 * 8) = v;
                }
                const bf16* Vsrc = Vbase + kt * 64;
#pragma unroll
                for (int c = 0; c < 8; ++c) {
                    int idx = c * 128 + t;
                    int row = idx >> 3, c8 = idx & 7;
                    int4 v = *(const int4*)(Vsrc + (size_t)row * N_TOK + c8 * 8);
                    *(int4*)(Vs + row * 72 + c8 * 8) = v;
                }
            }
            __syncthreads();
            f32x4 acc_s[4] = {};
#pragma unroll
            for (int ks = 0; ks < 6; ++ks) {
                bf16x8 bv[4];
#pragma unroll
                for (int j = 0; j < 4; ++j)
                    bv[j] = *(const bf16x8*)(Ks + (j * 16 + fr) * 200 + ks * 32 + fg * 8);
#pragma unroll
                for (int j = 0; j < 4; ++j)
                    acc_s[j] = __builtin_amdgcn_mfma_f32_16x16x32_bf16(aq[ks], bv[j], acc_s[j], 0, 0, 0);
            }
            if (kt == nkt - 1) {
                int colb = kt * 64;
                int rowb = qp * 32 + w * 16;
#pragma unroll
                for (int j = 0; j < 4; ++j)
#pragma unroll
                    for (int q = 0; q < 4; ++q)
                        if (colb + j * 16 + fr > rowb + fg * 4 + q)
                            acc_s[j][q] = -1e30f;
            }
#pragma unroll
            for (int q = 0; q < 4; ++q) {
                float tmax = fmaxf(fmaxf(acc_s[0][q], acc_s[1][q]),
                                   fmaxf(acc_s[2][q], acc_s[3][q]));
                tmax = fmaxf(tmax, __shfl_xor(tmax, 1, 64));
                tmax = fmaxf(tmax, __shfl_xor(tmax, 2, 64));
                tmax = fmaxf(tmax, __shfl_xor(tmax, 4, 64));
                tmax = fmaxf(tmax, __shfl_xor(tmax, 8, 64));
                float mn = fmaxf(m_r[q], tmax);
                float sc = __expf(m_r[q] - mn);
                m_r[q] = mn;
                float s0 = 0.f;
#pragma unroll
                for (int j = 0; j < 4; ++j) {
                    float pv = __expf(acc_s[j][q] - mn);
                    acc_s[j][q] = pv;
                    s0 += pv;
                }
                s0 += __shfl_xor(s0, 1, 64);
                s0 += __shfl_xor(s0, 2, 64);
                s0 += __shfl_xor(s0, 4, 64);
                s0 += __shfl_xor(s0, 8, 64);
                l_r[q] = l_r[q] * sc + s0;
#pragma unroll
                for (int jo = 0; jo < 8; ++jo) acc_o[jo][q] *= sc;
            }
#pragma unroll
            for (int j = 0; j < 4; ++j)
#pragma unroll
                for (int q = 0; q < 4; ++q)
                    Ps[(w * 16 + fg * 4 + q) * 72 + j * 16 + fr] = (short)f2bfu(acc_s[j][q]);
#pragma unroll
            for (int ks2 = 0; ks2 < 2; ++ks2) {
                bf16x8 pa = *(const bf16x8*)(Ps + (w * 16 + fr) * 72 + ks2 * 32 + fg * 8);
#pragma unroll
                for (int jo = 0; jo < 8; ++jo) {
                    bf16x8 vb = *(const bf16x8*)(Vs + (jo * 16 + fr) * 72 + ks2 * 32 + fg * 8);
                    acc_o[jo] = __builtin_amdgcn_mfma_f32_16x16x32_bf16(pa, vb, acc_o[jo], 0, 0, 0);
                }
            }
        }
        bf16* obase = aout + (size_t)(qp * 32 + w * 16) * (NH * VH) + h * VH;
#pragma unroll
        for (int q = 0; q < 4; ++q) {
            float inv = 1.f / l_r[q];
#pragma unroll
            for (int jo = 0; jo < 8; ++jo)
                obase[(size_t)(fg * 4 + q) * (NH * VH) + jo * 16 + fr] =
                    __float2bfloat16(acc_o[jo][q] * inv);
        }
    }
}

extern "C" void kernel_launch(void* const* d_in, const int* in_sizes, int n_in,
                              void* d_out, int out_size, void* d_ws, size_t ws_size,
                              hipStream_t stream) {
    (void)in_sizes; (void)n_in; (void)out_size;
    const int* tokens = (const int*)d_in[0];
    const float* emb = (const float*)d_in[1];
    const float* qW = (const float*)d_in[2];
    const float* kvaW = (const float*)d_in[3];
    const float* kvnorm_w = (const float*)d_in[4];
    const float* kvbW = (const float*)d_in[5];
    const float* oW = (const float*)d_in[6];
    const float* w1 = (const float*)d_in[7];
    const float* w2 = (const float*)d_in[8];
    const float* w3 = (const float*)d_in[9];
    const float* attn_norm_w = (const float*)d_in[10];
    const float* ffn_norm_w = (const float*)d_in[11];
    const float* norm_w = (const float*)d_in[12];
    const float* outW = (const float*)d_in[13];
    const float* rope_cos = (const float*)d_in[14];
    const float* rope_sin = (const float*)d_in[15];

    hipFuncSetAttribute((const void*)k_mm8<0>, hipFuncAttributeMaxDynamicSharedMemorySize, 131072);
    hipFuncSetAttribute((const void*)k_mm8<3>, hipFuncAttributeMaxDynamicSharedMemorySize, 131072);
    hipFuncSetAttribute((const void*)k_mm<0>, hipFuncAttributeMaxDynamicSharedMemorySize, 65536);
    hipFuncSetAttribute((const void*)k_mm<1>, hipFuncAttributeMaxDynamicSharedMemorySize, 65536);
    hipFuncSetAttribute((const void*)k_mm<4>, hipFuncAttributeMaxDynamicSharedMemorySize, 65536);

    float* ws = (float*)d_ws;
    size_t off = 0;
    auto allocF = [&](size_t fl) { float* p = ws + off; off += (fl + 63) & ~63ULL; return p; };
    float* h    = allocF(4194304);            // [2048][2048] f32
    bf16* xb    = (bf16*)allocF(2097152);     // [2048][2048] bf16
    bf16* cb    = (bf16*)allocF(524288);      // [2048][512] bf16
    bf16* qb    = (bf16*)allocF(3145728);     // [16][2048][192] bf16
    bf16* Kb    = (bf16*)allocF(3145728);     // [16][2048][192] bf16
    bf16* Vt    = (bf16*)allocF(2097152);     // [16][128][2048] bf16
    bf16* aout  = (bf16*)allocF(2097152);     // [2048][2048] bf16
    bf16* qWt   = (bf16*)allocF(3145728);     // [3072][2048]
    bf16* kvaWt = (bf16*)allocF(655360);      // [640][2048]
    bf16* kvbWt = (bf16*)allocF(1048576);     // [4096][512]
    bf16* oWt   = (bf16*)allocF(2097152);     // [2048][2048]
    bf16* w12t  = (bf16*)allocF(11534336);    // [11264][2048] interleaved w1/w2
    bf16* w3t   = (bf16*)allocF(5767168);     // [2048][5632]
    float* scr  = ws + off;
    size_t availF = (ws_size / 4 > off) ? ws_size / 4 - off : 0;

    int oc = 25;
    {
        const int ocs[3] = {1, 5, 25};
        for (int i = 0; i < 3; ++i) {
            size_t need = 7602176;                         // qkv [2048][3712] f32
            size_t a2 = (size_t)32768000 / ocs[i];         // outW chunk (bf16, in floats)
            if (a2 > need) need = a2;
            if (5767168 > need) need = 5767168;            // fbig [2048][5632] bf16
            if (need <= availF) { oc = ocs[i]; break; }
        }
    }
    float* qkv  = scr;                          // [2048][3712] f32 (dead after qpack)
    bf16* fbig  = (bf16*)scr;                   // [2048][5632] bf16
    bf16* oWtc  = (bf16*)scr;                   // outW chunk [cn][2048]

    k_embed<<<N_TOK, 256, 0, stream>>>(tokens, emb, h);

    for (int l = 0; l < NLAYER; ++l) {
        ConvBatch cbt;
        const float* srcs[7] = {qW + (size_t)l * DIM * 3072, kvaW + (size_t)l * DIM * 576,
                                kvbW + (size_t)l * 512 * 4096, oW + (size_t)l * 2048 * 2048,
                                w1 + (size_t)l * DIM * INTER, w2 + (size_t)l * DIM * INTER,
                                w3 + (size_t)l * INTER * DIM};
        bf16* dsts[7]  = {qWt, kvaWt, kvbWt, oWt, w12t, w12t, w3t};
        int Ks[7]   = {2048, 2048, 512, 2048, 2048, 2048, 5632};
        int ldws[7] = {3072, 576, 4096, 2048, 5632, 5632, 2048};
        int ncs[7]  = {3072, 576, 4096, 2048, 5632, 5632, 2048};
        int ilvs[7] = {-1, -1, -1, -1, 0, 16, -1};
        int nbxs[7] = {48, 10, 64, 32, 88, 88, 32};
        int nbys[7] = {64, 64, 16, 64, 64, 64, 176};
        int tot = 0;
        for (int i = 0; i < 7; ++i) {
            cbt.W[i] = srcs[i]; cbt.Out[i] = dsts[i];
            cbt.K[i] = Ks[i]; cbt.ldw[i] = ldws[i]; cbt.ncols[i] = ncs[i];
            cbt.ilv[i] = ilvs[i]; cbt.nbx[i] = nbxs[i];
            cbt.blk0[i] = tot; tot += nbxs[i] * nbys[i];
        }
        cbt.blk0[7] = tot;
        k_convAll<<<dim3(tot), 256, 0, stream>>>(cbt);

        k_rmsnorm<<<N_TOK, 256, 0, stream>>>(h, 2048, 0, xb, attn_norm_w + (size_t)l * DIM, 2048);
        // merged q + kva projection: N = 3072 + 640 = 3712
        k_mm<0><<<dim3(464), 256, 65536, stream>>>(xb, qWt, qkv, nullptr, 3712, 2048, 2048, 2048, 3712);
        k_qpack<<<N_TOK, 256, 0, stream>>>(qkv, 3712, 3072, rope_cos, rope_sin, qb, Kb,
                                           kvnorm_w + (size_t)l * KVR, cb);
        // qkv now dead; kvb GEMM writes Kb-nope + Vt (transposed) directly (OUT=4)
        k_mm<4><<<dim3(512), 256, 65536, stream>>>(cb, kvbWt, Kb, Vt, 4096, 512, 512, 512, 0);
        k_flash<<<dim3(NH, 32), 128, 0, stream>>>(qb, Kb, Vt, aout);
        k_mm<1><<<dim3(256), 256, 65536, stream>>>(aout, oWt, h, nullptr, 2048, 2048, 2048, 2048, 2048);

        k_rmsnorm<<<N_TOK, 256, 0, stream>>>(h, 2048, 0, xb, ffn_norm_w + (size_t)l * DIM, 2048);
        // merged w1+w2 (interleaved ilv=16) with fused silu epilogue -> fbig [2048][5632] bf16
        k_mm8<3><<<dim3(352), 512, 131072, stream>>>(xb, w12t, fbig, 2048, 2048, 2048, 5632);
        k_mm<1><<<dim3(256), 256, 65536, stream>>>(fbig, w3t, h, nullptr, 2048, 5632, 5632, 5632, 2048);
    }
    k_rmsnorm<<<N_TOK, 256, 0, stream>>>(h, 2048, 0, xb, norm_w, 2048);
    int cn = 32000 / oc;
    for (int c2 = 0; c2 < oc; ++c2) {
        k_convT<<<dim3(cn / 64, 64), 256, 0, stream>>>(outW, oWtc, 2048, 32000, cn, c2 * cn, -1);
        k_mm8<0><<<dim3(8 * (cn / 256)), 512, 131072, stream>>>(
            xb, oWtc, (float*)d_out + (size_t)c2 * cn, 2048, 2048, 2048, 32000);
    }
}